// Round 10
// baseline (80.534 us; speedup 1.0000x reference)
//
#include <hip/hip_runtime.h>
#include <stdint.h>

// Problem constants
#define NSLICE 64               // B*C
#define N_ELEM 262144           // 64^3 per slice
#define K_TOP  131072           // ceil(0.5*N)
#define INV_KB (1.0f / (131072.0f * 16.0f))

#define NB     2048             // sample buckets: bits 30..20 of bits(|d|)
#define SHIFT  20

// Sampling: 4 chunks of 1024 contiguous elements per slice = 1/64 of data
#define SNCH    4
#define SSTRIDE (N_ELEM / SNCH)   // 65536
#define RANK_A  2048              // ascending 0-indexed sampled rank of k-th largest
#define BLK    256                // thresh kernel block size

// Main pass: 2048 blocks x 256 threads; 8 float4-pairs per thread,
// issued via inline asm (16 loads in flight), consumed behind counted vmcnt.
#define BLK_M   256
#define CPB     32
#define CHUNK   (N_ELEM / CPB)      // 8192 elements = 2048 float4 per array

__device__ __forceinline__ unsigned int absbits(float d) {
    return __float_as_uint(d) & 0x7fffffffu;
}

// ---- 1. Sampled histogram -> interpolated scalar threshold t'^2 -----------
__global__ __launch_bounds__(BLK) void k_thresh(const float* __restrict__ in,
                                                const float* __restrict__ lab,
                                                float* __restrict__ t2arr,
                                                float* __restrict__ sliceS,
                                                unsigned int* __restrict__ sliceC) {
    __shared__ unsigned int hc[NB];
    __shared__ unsigned int part[BLK];
    __shared__ unsigned int pref[BLK];
    const int tid = threadIdx.x;
    const int slice = blockIdx.x;
    for (int i = tid; i < NB; i += BLK) hc[i] = 0u;
    if (tid == 0) sliceS[slice] = 0.0f;
    if (tid == 1) sliceC[slice] = 0u;
    __syncthreads();
#pragma unroll
    for (int j = 0; j < SNCH; ++j) {
        const long base = (long)slice * N_ELEM + (long)j * SSTRIDE;
        const float4 a = ((const float4*)(in + base))[tid];
        const float4 b = ((const float4*)(lab + base))[tid];
        atomicAdd(&hc[absbits(a.x - b.x) >> SHIFT], 1u);
        atomicAdd(&hc[absbits(a.y - b.y) >> SHIFT], 1u);
        atomicAdd(&hc[absbits(a.z - b.z) >> SHIFT], 1u);
        atomicAdd(&hc[absbits(a.w - b.w) >> SHIFT], 1u);
    }
    __syncthreads();
    const int G = NB / BLK;   // 8 buckets/thread, ascending
    unsigned int loc[NB / BLK];
    unsigned int s = 0;
#pragma unroll
    for (int j = 0; j < G; ++j) {
        loc[j] = hc[tid * G + j];
        s += loc[j];
    }
    part[tid] = s;
    __syncthreads();
    if (tid == 0) {
        unsigned int c = 0;
        for (int i = 0; i < BLK; ++i) { pref[i] = c; c += part[i]; }
    }
    __syncthreads();
    unsigned int cum = pref[tid];
#pragma unroll
    for (int j = 0; j < G; ++j) {
        const unsigned int c = loc[j];
        if (cum <= RANK_A && RANK_A < cum + c) {
            const unsigned int p = (unsigned int)(tid * G + j);
            const float f = (float)(RANK_A - cum) / (float)c;
            const unsigned int tbits = (p << SHIFT)
                                     + (unsigned int)(f * (float)(1u << SHIFT));
            const float t = __uint_as_float(tbits);
            t2arr[slice] = t * t;
        }
        cum += c;
    }
}

// Issue one 16B load: dst <- mem[sbase + voff]  (saddr form, 32-bit voffset)
#define GLD(dst, voff, sbase) \
    asm volatile("global_load_dwordx4 %0, %1, %2" \
                 : "=v"(dst) : "v"(voff), "s"(sbase) : "memory")

// Counted wait + scheduling fence (rule #18: VALU can hoist past asm waitcnt)
#define WAITV(n) do { \
    asm volatile("s_waitcnt vmcnt(" #n ")" ::: "memory"); \
    __builtin_amdgcn_sched_barrier(0); \
} while (0)

// Consume position j: 8 predicated compare-accumulates (two float4s)
#define CONS(j) { \
    { float d = A##j.x - B##j.x; float sq = d * d; bool g = sq > t2; \
      S0 += g ? sq : 0.0f; C0 += g ? 1u : 0u; } \
    { float d = A##j.y - B##j.y; float sq = d * d; bool g = sq > t2; \
      S1 += g ? sq : 0.0f; C1 += g ? 1u : 0u; } \
    { float d = A##j.z - B##j.z; float sq = d * d; bool g = sq > t2; \
      S0 += g ? sq : 0.0f; C0 += g ? 1u : 0u; } \
    { float d = A##j.w - B##j.w; float sq = d * d; bool g = sq > t2; \
      S1 += g ? sq : 0.0f; C1 += g ? 1u : 0u; } }

// ---- 2. Main pass: asm-pinned 16-deep load pipeline -----------------------
__global__ __launch_bounds__(BLK_M, 2) void k_main(const float* __restrict__ in,
                                                   const float* __restrict__ lab,
                                                   const float* __restrict__ t2arr,
                                                   float* __restrict__ sliceS,
                                                   unsigned int* __restrict__ sliceC) {
    const int tid = threadIdx.x;
    const int slice = blockIdx.y;
    const float t2 = t2arr[slice];
    const unsigned long byteBase =
        ((unsigned long)slice * N_ELEM + (unsigned long)blockIdx.x * CHUNK) * 4ul;
    const char* pA = (const char*)in + byteBase;    // uniform -> SGPR pair
    const char* pB = (const char*)lab + byteBase;

    float S0 = 0.0f, S1 = 0.0f;
    unsigned int C0 = 0u, C1 = 0u;

    float4 A0, A1, A2, A3, A4, A5, A6, A7;
    float4 B0, B1, B2, B3, B4, B5, B6, B7;

    // Issue all 16 loads back-to-back (asm volatile order preserved).
    unsigned int off = (unsigned int)tid * 16u;     // position stride 4096 B
    GLD(A0, off, pA); GLD(B0, off, pB); off += 4096u;
    GLD(A1, off, pA); GLD(B1, off, pB); off += 4096u;
    GLD(A2, off, pA); GLD(B2, off, pB); off += 4096u;
    GLD(A3, off, pA); GLD(B3, off, pB); off += 4096u;
    GLD(A4, off, pA); GLD(B4, off, pB); off += 4096u;
    GLD(A5, off, pA); GLD(B5, off, pB); off += 4096u;
    GLD(A6, off, pA); GLD(B6, off, pB); off += 4096u;
    GLD(A7, off, pA); GLD(B7, off, pB);

    // Consume oldest-first behind counted waits (never drain to 0 early).
    WAITV(14); CONS(0);
    WAITV(12); CONS(1);
    WAITV(10); CONS(2);
    WAITV(8);  CONS(3);
    WAITV(6);  CONS(4);
    WAITV(4);  CONS(5);
    WAITV(2);  CONS(6);
    WAITV(0);  CONS(7);

    float S = S0 + S1;
    unsigned int C = C0 + C1;
#pragma unroll
    for (int o = 32; o > 0; o >>= 1) {
        S += __shfl_down(S, o);
        C += __shfl_down(C, o);
    }
    if ((tid & 63) == 0) {      // one pair of global atomics per wave
        atomicAdd(&sliceS[slice], S);
        atomicAdd(&sliceC[slice], C);
    }
}

// ---- 3. Final: boundary-corrected estimator, 64-lane reduce ---------------
__global__ __launch_bounds__(64) void k_final(const float* __restrict__ sliceS,
                                              const unsigned int* __restrict__ sliceC,
                                              const float* __restrict__ t2arr,
                                              float* __restrict__ out) {
    const int t = threadIdx.x;   // one lane per slice
    float S = sliceS[t] + ((float)K_TOP - (float)sliceC[t]) * t2arr[t];
#pragma unroll
    for (int o = 32; o > 0; o >>= 1) S += __shfl_down(S, o);
    if (t == 0) out[0] = S * INV_KB;
}

// ---------------------------------------------------------------------------
extern "C" void kernel_launch(void* const* d_in, const int* in_sizes, int n_in,
                              void* d_out, int out_size, void* d_ws, size_t ws_size,
                              hipStream_t stream) {
    const float* in = (const float*)d_in[0];
    const float* lab = (const float*)d_in[1];
    float* out = (float*)d_out;

    unsigned char* w = (unsigned char*)d_ws;
    // ws layout (all written in-stream; no memsets needed):
    //  [0, 256)       t2arr  : 64 f32 (always written by k_thresh)
    //  [256, 512)     sliceS : 64 f32 (zeroed by k_thresh)
    //  [512, 768)     sliceC : 64 u32 (zeroed by k_thresh)
    float* t2arr = (float*)(w);
    float* sliceS = (float*)(w + 256);
    unsigned int* sliceC = (unsigned int*)(w + 512);

    k_thresh<<<NSLICE, BLK, 0, stream>>>(in, lab, t2arr, sliceS, sliceC);
    k_main<<<dim3(CPB, NSLICE), BLK_M, 0, stream>>>(in, lab, t2arr, sliceS, sliceC);
    k_final<<<1, 64, 0, stream>>>(sliceS, sliceC, t2arr, out);
}

// Round 11
// 40.863 us; speedup vs baseline: 1.9709x; 1.9709x over previous
//
#include <hip/hip_runtime.h>
#include <stdint.h>

// Problem constants
#define NSLICE 64               // B*C
#define N_ELEM 262144           // 64^3 per slice
#define K_TOP  131072           // ceil(0.5*N)
#define INV_KB (1.0f / (131072.0f * 16.0f))

#define NB     2048             // sample buckets: bits 30..20 of bits(|d|)
#define SHIFT  20

// Sampling: 4 chunks of 1024 contiguous elements per slice = 1/64 of data
#define SNCH    4
#define SSTRIDE (N_ELEM / SNCH)   // 65536
#define RANK_A  2048              // ascending 0-indexed sampled rank of k-th largest
#define BLK    256                // thresh kernel block size

// Main pass: 512 blocks (2/CU) x 256 threads; global_load_lds double-buffered
// pipeline. Tile = 2048 f32 per array (8 KB); 16 tiles per block.
#define BLK_M   256
#define CPB     8
#define CHUNK   (N_ELEM / CPB)      // 32768 f32 per array per block
#define TILE_F4 512                 // float4s per array per tile (8 KB)
#define NTILE   16                  // CHUNK / 2048

__device__ __forceinline__ unsigned int absbits(float d) {
    return __float_as_uint(d) & 0x7fffffffu;
}

// ---- 1. Sampled histogram -> interpolated scalar threshold t'^2 -----------
__global__ __launch_bounds__(BLK) void k_thresh(const float* __restrict__ in,
                                                const float* __restrict__ lab,
                                                float* __restrict__ t2arr,
                                                float* __restrict__ sliceS,
                                                unsigned int* __restrict__ sliceC) {
    __shared__ unsigned int hc[NB];
    __shared__ unsigned int part[BLK];
    __shared__ unsigned int pref[BLK];
    const int tid = threadIdx.x;
    const int slice = blockIdx.x;
    for (int i = tid; i < NB; i += BLK) hc[i] = 0u;
    if (tid == 0) sliceS[slice] = 0.0f;
    if (tid == 1) sliceC[slice] = 0u;
    __syncthreads();
#pragma unroll
    for (int j = 0; j < SNCH; ++j) {
        const long base = (long)slice * N_ELEM + (long)j * SSTRIDE;
        const float4 a = ((const float4*)(in + base))[tid];
        const float4 b = ((const float4*)(lab + base))[tid];
        atomicAdd(&hc[absbits(a.x - b.x) >> SHIFT], 1u);
        atomicAdd(&hc[absbits(a.y - b.y) >> SHIFT], 1u);
        atomicAdd(&hc[absbits(a.z - b.z) >> SHIFT], 1u);
        atomicAdd(&hc[absbits(a.w - b.w) >> SHIFT], 1u);
    }
    __syncthreads();
    const int G = NB / BLK;   // 8 buckets/thread, ascending
    unsigned int loc[NB / BLK];
    unsigned int s = 0;
#pragma unroll
    for (int j = 0; j < G; ++j) {
        loc[j] = hc[tid * G + j];
        s += loc[j];
    }
    part[tid] = s;
    __syncthreads();
    if (tid == 0) {
        unsigned int c = 0;
        for (int i = 0; i < BLK; ++i) { pref[i] = c; c += part[i]; }
    }
    __syncthreads();
    unsigned int cum = pref[tid];
#pragma unroll
    for (int j = 0; j < G; ++j) {
        const unsigned int c = loc[j];
        if (cum <= RANK_A && RANK_A < cum + c) {
            const unsigned int p = (unsigned int)(tid * G + j);
            const float f = (float)(RANK_A - cum) / (float)c;
            const unsigned int tbits = (p << SHIFT)
                                     + (unsigned int)(f * (float)(1u << SHIFT));
            const float t = __uint_as_float(tbits);
            t2arr[slice] = t * t;
        }
        cum += c;
    }
}

// Direct global->LDS DMA, 16 B per lane. LDS dest must be wave-uniform base.
#define GLDS(g, l) __builtin_amdgcn_global_load_lds( \
    (const __attribute__((address_space(1))) void*)(g), \
    (__attribute__((address_space(3))) void*)(l), 16, 0, 0)

// Counted wait + scheduling fence
#define WAITV(n) do { \
    asm volatile("s_waitcnt vmcnt(" #n ")" ::: "memory"); \
    __builtin_amdgcn_sched_barrier(0); \
} while (0)

// ---- 2. Main pass: gload_lds double-buffer, counted vmcnt, raw barriers ---
__global__ __launch_bounds__(BLK_M) void k_main(const float* __restrict__ in,
                                                const float* __restrict__ lab,
                                                const float* __restrict__ t2arr,
                                                float* __restrict__ sliceS,
                                                unsigned int* __restrict__ sliceC) {
    __shared__ float4 sA[2][TILE_F4];
    __shared__ float4 sB[2][TILE_F4];
    const int tid = threadIdx.x;
    const int slice = blockIdx.y;
    const float t2 = t2arr[slice];
    const long base = (long)slice * N_ELEM + (long)blockIdx.x * CHUNK;
    const char* gA = (const char*)(in + base);
    const char* gB = (const char*)(lab + base);
    const int wofs = (tid >> 6) * 1024;   // wave-uniform LDS offset
    const int tofs = tid * 16;            // per-lane global offset

    float S0 = 0.0f, S1 = 0.0f;
    unsigned int C0 = 0u, C1 = 0u;

    // Stage tile t (8 KB per array = 2 calls of 4 KB) into buffer b.
#define STAGE(t, b) do { \
    const char* ga = gA + (size_t)(t) * 8192; \
    const char* gb = gB + (size_t)(t) * 8192; \
    char* la = (char*)&sA[b][0] + wofs; \
    char* lb = (char*)&sB[b][0] + wofs; \
    GLDS(ga + tofs,        la); \
    GLDS(ga + tofs + 4096, la + 4096); \
    GLDS(gb + tofs,        lb); \
    GLDS(gb + tofs + 4096, lb + 4096); \
} while (0)

    // Consume buffer b from LDS (4x ds_read_b128 + 8 compare-accumulates).
#define CONSUME(b) do { \
    const float4 a0 = sA[b][tid]; \
    const float4 b0 = sB[b][tid]; \
    const float4 a1 = sA[b][tid + 256]; \
    const float4 b1 = sB[b][tid + 256]; \
    { float d = a0.x - b0.x; float sq = d * d; bool g = sq > t2; \
      S0 += g ? sq : 0.0f; C0 += g ? 1u : 0u; } \
    { float d = a0.y - b0.y; float sq = d * d; bool g = sq > t2; \
      S1 += g ? sq : 0.0f; C1 += g ? 1u : 0u; } \
    { float d = a0.z - b0.z; float sq = d * d; bool g = sq > t2; \
      S0 += g ? sq : 0.0f; C0 += g ? 1u : 0u; } \
    { float d = a0.w - b0.w; float sq = d * d; bool g = sq > t2; \
      S1 += g ? sq : 0.0f; C1 += g ? 1u : 0u; } \
    { float d = a1.x - b1.x; float sq = d * d; bool g = sq > t2; \
      S0 += g ? sq : 0.0f; C0 += g ? 1u : 0u; } \
    { float d = a1.y - b1.y; float sq = d * d; bool g = sq > t2; \
      S1 += g ? sq : 0.0f; C1 += g ? 1u : 0u; } \
    { float d = a1.z - b1.z; float sq = d * d; bool g = sq > t2; \
      S0 += g ? sq : 0.0f; C0 += g ? 1u : 0u; } \
    { float d = a1.w - b1.w; float sq = d * d; bool g = sq > t2; \
      S1 += g ? sq : 0.0f; C1 += g ? 1u : 0u; } \
} while (0)

    STAGE(0, 0);
    STAGE(1, 1);                          // 8 loads in flight (32 KB/block)
#pragma unroll
    for (int t = 0; t < NTILE - 2; t += 2) {
        WAITV(4);                         // tile t landed; t+1 still flying
        __builtin_amdgcn_s_barrier();
        CONSUME(0);
        __builtin_amdgcn_s_barrier();     // all waves done reading buf0
        STAGE(t + 2, 0);                  // refill buf0 (back to 8 in flight)
        WAITV(4);                         // tile t+1 landed; t+2 flying
        __builtin_amdgcn_s_barrier();
        CONSUME(1);
        __builtin_amdgcn_s_barrier();
        STAGE(t + 3, 1);
    }
    WAITV(4);                             // tile 14 landed
    __builtin_amdgcn_s_barrier();
    CONSUME(0);
    WAITV(0);                             // tile 15 landed
    __builtin_amdgcn_s_barrier();
    CONSUME(1);

    float S = S0 + S1;
    unsigned int C = C0 + C1;
#pragma unroll
    for (int o = 32; o > 0; o >>= 1) {
        S += __shfl_down(S, o);
        C += __shfl_down(C, o);
    }
    if ((tid & 63) == 0) {      // one pair of global atomics per wave
        atomicAdd(&sliceS[slice], S);
        atomicAdd(&sliceC[slice], C);
    }
#undef STAGE
#undef CONSUME
}

// ---- 3. Final: boundary-corrected estimator, 64-lane reduce ---------------
__global__ __launch_bounds__(64) void k_final(const float* __restrict__ sliceS,
                                              const unsigned int* __restrict__ sliceC,
                                              const float* __restrict__ t2arr,
                                              float* __restrict__ out) {
    const int t = threadIdx.x;   // one lane per slice
    float S = sliceS[t] + ((float)K_TOP - (float)sliceC[t]) * t2arr[t];
#pragma unroll
    for (int o = 32; o > 0; o >>= 1) S += __shfl_down(S, o);
    if (t == 0) out[0] = S * INV_KB;
}

// ---------------------------------------------------------------------------
extern "C" void kernel_launch(void* const* d_in, const int* in_sizes, int n_in,
                              void* d_out, int out_size, void* d_ws, size_t ws_size,
                              hipStream_t stream) {
    const float* in = (const float*)d_in[0];
    const float* lab = (const float*)d_in[1];
    float* out = (float*)d_out;

    unsigned char* w = (unsigned char*)d_ws;
    // ws layout (all written in-stream; no memsets needed):
    //  [0, 256)       t2arr  : 64 f32 (always written by k_thresh)
    //  [256, 512)     sliceS : 64 f32 (zeroed by k_thresh)
    //  [512, 768)     sliceC : 64 u32 (zeroed by k_thresh)
    float* t2arr = (float*)(w);
    float* sliceS = (float*)(w + 256);
    unsigned int* sliceC = (unsigned int*)(w + 512);

    k_thresh<<<NSLICE, BLK, 0, stream>>>(in, lab, t2arr, sliceS, sliceC);
    k_main<<<dim3(CPB, NSLICE), BLK_M, 0, stream>>>(in, lab, t2arr, sliceS, sliceC);
    k_final<<<1, 64, 0, stream>>>(sliceS, sliceC, t2arr, out);
}